// Round 3
// baseline (323.925 us; speedup 1.0000x reference)
//
#include <hip/hip_runtime.h>
#include <hip/hip_bf16.h>

// GraphConvolution: out = relu( (W@x + b) @ adj^T + x ), B=4096, C=256, N=25.
// R3: two-kernel streaming split.
//   prep: W fp32->bf16 (ws), adj row-sums (ws).
//   agg:  y[b][m][c] = sum_n adj[m,n]*x[b,c,n]  (MFMA, bf16, y in ws; m padded to 32)
//   gemm: out[b,o,m] = relu( sum_c Wb[o,c]*y[b,m,c... (B-frag from global y)
//                            + bias[o]*adjS[m] + x[b,o,m] )
// gemm has ZERO LDS and ZERO barriers: all operands stream from global/L2/L3
// with deep prefetch. Rationale: R1->R2 showed +60% occupancy = 0% speedup;
// the fused 3-barrier LDS-round-trip chain was the sink, not occupancy.

#define BATCH 4096
#define C 256
#define N 25
#define XS 40          // xbf/adjbf row stride (bf16), 80 B, 16B-aligned
#define YB (32 * 256)  // y elements per batch: 32 m-rows x 256 c, contiguous
#define YS 264         // fallback-kernel ys stride

typedef __bf16 bf16x8 __attribute__((ext_vector_type(8)));
typedef float f32x4 __attribute__((ext_vector_type(4)));

// ---- prep: Wb = bf16(W); adjS[m] = rowsum(adj) (m>=25 -> 0) ----
__global__ void prep_kernel(const float* __restrict__ W, const float* __restrict__ adj,
                            __bf16* __restrict__ Wb, float* __restrict__ adjS) {
    int i = blockIdx.x * 256 + threadIdx.x;
    Wb[i] = (__bf16)W[i];
    if (blockIdx.x == 0 && threadIdx.x < 32) {
        float s = 0.f;
        if (threadIdx.x < N)
            for (int n = 0; n < N; ++n) s += adj[threadIdx.x * N + n];
        adjS[threadIdx.x] = s;
    }
}

// ---- agg: per-b MFMA aggregation, coalesced dump of y[b] (16 KiB) ----
__global__ __launch_bounds__(256) void agg_kernel(
    const float* __restrict__ x, const float* __restrict__ adj,
    __bf16* __restrict__ y)
{
    __shared__ __align__(16) unsigned char smem_u[C * XS * 2]; // 20480 B: xbf, then ysd
    __shared__ __align__(16) __bf16 adjbf[32 * XS];
    __bf16* xbf = (__bf16*)smem_u;  // [C][XS], n=25..31 zeroed
    __bf16* ysd = (__bf16*)smem_u;  // [32][256] contiguous (16384 B), aliases xbf

    const int tid = threadIdx.x;
    const int b = blockIdx.x;
    const float* xb = x + (size_t)b * (C * N);

    { // stage x -> bf16 LDS (coalesced float4 in, scattered b16 LDS writes)
        const float4* xb4 = (const float4*)xb;
        for (int i = tid; i < (C * N) / 4; i += 256) {
            float4 v = xb4[i];
            int e = i * 4;
            int c = e / N, n = e - c * N;
            float f[4] = {v.x, v.y, v.z, v.w};
            #pragma unroll
            for (int q = 0; q < 4; ++q) {
                xbf[c * XS + n] = (__bf16)f[q];
                ++n; if (n == N) { n = 0; ++c; }
            }
        }
    }
    #pragma unroll
    for (int n = N; n < 32; ++n) xbf[tid * XS + n] = (__bf16)0.f;

    for (int e = tid; e < N * N; e += 256) {
        int m = e / N, n = e - m * N;
        adjbf[m * XS + n] = (__bf16)adj[e];
    }
    if (tid < N) {
        #pragma unroll
        for (int n = N; n < 32; ++n) adjbf[tid * XS + n] = (__bf16)0.f;
    } else if (tid < 32) {
        #pragma unroll
        for (int n = 0; n < 32; ++n) adjbf[tid * XS + n] = (__bf16)0.f;
    }
    __syncthreads();

    const int wv = tid >> 6, lane = tid & 63;
    const int quad = lane >> 4, l15 = lane & 15;

    // D[m][c] = sum_n adj[m][n] * x[c][n]; wave wv owns c in [wv*64, wv*64+64)
    f32x4 yacc[4][2];
    {
        bf16x8 a0 = *(const bf16x8*)&adjbf[l15 * XS + quad * 8];
        bf16x8 a1 = *(const bf16x8*)&adjbf[(16 + l15) * XS + quad * 8]; // rows 25..31 zero
        #pragma unroll
        for (int ctl = 0; ctl < 4; ++ctl) {
            int c = wv * 64 + ctl * 16 + l15;
            bf16x8 xf = *(const bf16x8*)&xbf[c * XS + quad * 8];
            yacc[ctl][0] = __builtin_amdgcn_mfma_f32_16x16x32_bf16(a0, xf, (f32x4)0.f, 0, 0, 0);
            yacc[ctl][1] = __builtin_amdgcn_mfma_f32_16x16x32_bf16(a1, xf, (f32x4)0.f, 0, 0, 0);
        }
    }
    __syncthreads();  // xbf reads done -> safe to alias with ysd

    // C-layout (col c = tile+l15, row m = quad*4+r) -> ysd[m][c] bf16
    #pragma unroll
    for (int ctl = 0; ctl < 4; ++ctl) {
        int c = wv * 64 + ctl * 16 + l15;
        #pragma unroll
        for (int mt = 0; mt < 2; ++mt)
            #pragma unroll
            for (int r = 0; r < 4; ++r) {
                int m = mt * 16 + quad * 4 + r;
                ysd[m * 256 + c] = (__bf16)yacc[ctl][mt][r];
            }
    }
    __syncthreads();

    // coalesced dump: 16384 B, lane-contiguous b128 (LDS addr = linear index)
    {
        const bf16x8* s8 = (const bf16x8*)ysd;
        bf16x8* g8 = (bf16x8*)(y + (size_t)b * YB);
        #pragma unroll
        for (int q = 0; q < 4; ++q) g8[q * 256 + tid] = s8[q * 256 + tid];
    }
}

// ---- gemm: out[o][m] = relu( sum_c Wb[o][c]*y[m][c] + bias[o]*adjS[m] + x[o][m] )
// no LDS, no barriers; B-frags prefetched from global y, A-frags L2-hot Wb.
__global__ __launch_bounds__(256) void gemm_kernel(
    const float* __restrict__ x, const float* __restrict__ bias,
    const float* __restrict__ adjS, const __bf16* __restrict__ Wb,
    const __bf16* __restrict__ y, float* __restrict__ out)
{
    const int tid = threadIdx.x, b = blockIdx.x;
    const int wv = tid >> 6, lane = tid & 63;
    const int quad = lane >> 4, l15 = lane & 15;
    const int o0 = wv * 64;
    const __bf16* yb = y + (size_t)b * YB;

    // prefetch all 16 B-fragments: bf[kk][mt] = B[k=c][col=m], 16 B each
    bf16x8 bf[8][2];
    #pragma unroll
    for (int kk = 0; kk < 8; ++kk)
        #pragma unroll
        for (int mt = 0; mt < 2; ++mt)
            bf[kk][mt] = *(const bf16x8*)&yb[(mt * 16 + l15) * 256 + kk * 32 + quad * 8];

    f32x4 acc[4][2];
    #pragma unroll
    for (int ot = 0; ot < 4; ++ot)
        #pragma unroll
        for (int mt = 0; mt < 2; ++mt) acc[ot][mt] = (f32x4)0.f;

    #pragma unroll
    for (int kk = 0; kk < 8; ++kk) {
        const int k = kk * 32 + quad * 8;
        #pragma unroll
        for (int ot = 0; ot < 4; ++ot) {
            bf16x8 af = *(const bf16x8*)&Wb[(size_t)(o0 + ot * 16 + l15) * C + k];
            #pragma unroll
            for (int mt = 0; mt < 2; ++mt)
                acc[ot][mt] = __builtin_amdgcn_mfma_f32_16x16x32_bf16(af, bf[kk][mt], acc[ot][mt], 0, 0, 0);
        }
    }

    const float* xb = x + (size_t)b * (C * N);
    float* outb = out + (size_t)b * (C * N);
    const float aS0 = adjS[l15], aS1 = adjS[16 + l15];
    #pragma unroll
    for (int ot = 0; ot < 4; ++ot)
        #pragma unroll
        for (int r = 0; r < 4; ++r) {
            const int o = o0 + ot * 16 + quad * 4 + r;
            const float bia = bias[o];
            { // mt = 0: m = l15 < 16, always valid
                const int m = l15;
                float v = acc[ot][0][r] + bia * aS0 + xb[o * N + m];
                outb[o * N + m] = v > 0.f ? v : 0.f;
            }
            if (l15 < N - 16) { // mt = 1: m = 16 + l15
                const int m = 16 + l15;
                float v = acc[ot][1][r] + bia * aS1 + xb[o * N + m];
                outb[o * N + m] = v > 0.f ? v : 0.f;
            }
        }
}

// ---- fallback (R2 fused) if ws too small for y ----
__global__ __launch_bounds__(256) void gcn_fused_kernel(
    const float* __restrict__ x, const float* __restrict__ adj,
    const float* __restrict__ bias, const __bf16* __restrict__ Wb,
    float* __restrict__ out)
{
    __shared__ __align__(16) unsigned char smem_u[C * XS * 2];
    __shared__ __align__(16) __bf16 adjbf[32 * XS];
    __shared__ float adjS[32];
    __shared__ float biasS[C];
    __bf16* xbf = (__bf16*)smem_u;
    __bf16* ys  = (__bf16*)smem_u;

    const int tid = threadIdx.x;
    const int b = blockIdx.x;
    const float* xb = x + (size_t)b * (C * N);
    {
        const float4* xb4 = (const float4*)xb;
        for (int i = tid; i < (C * N) / 4; i += 256) {
            float4 v = xb4[i];
            int e = i * 4;
            int c = e / N, n = e - c * N;
            float f[4] = {v.x, v.y, v.z, v.w};
            #pragma unroll
            for (int q = 0; q < 4; ++q) {
                xbf[c * XS + n] = (__bf16)f[q];
                ++n; if (n == N) { n = 0; ++c; }
            }
        }
    }
    #pragma unroll
    for (int n = N; n < 32; ++n) xbf[tid * XS + n] = (__bf16)0.f;
    for (int e = tid; e < N * N; e += 256) {
        int m = e / N, n = e - m * N;
        adjbf[m * XS + n] = (__bf16)adj[e];
    }
    if (tid < N) {
        #pragma unroll
        for (int n = N; n < 32; ++n) adjbf[tid * XS + n] = (__bf16)0.f;
        float s = 0.f;
        for (int n = 0; n < N; ++n) s += adj[tid * N + n];
        adjS[tid] = s;
    } else if (tid < 32) {
        #pragma unroll
        for (int n = 0; n < 32; ++n) adjbf[tid * XS + n] = (__bf16)0.f;
        adjS[tid] = 0.f;
    }
    biasS[tid] = bias[tid];
    __syncthreads();

    const int wv = tid >> 6, lane = tid & 63;
    const int quad = lane >> 4, l15 = lane & 15;
    f32x4 yacc[4][2];
    {
        bf16x8 a0 = *(const bf16x8*)&adjbf[l15 * XS + quad * 8];
        bf16x8 a1 = *(const bf16x8*)&adjbf[(16 + l15) * XS + quad * 8];
        #pragma unroll
        for (int ctl = 0; ctl < 4; ++ctl) {
            int c = wv * 64 + ctl * 16 + l15;
            bf16x8 xf = *(const bf16x8*)&xbf[c * XS + quad * 8];
            yacc[ctl][0] = __builtin_amdgcn_mfma_f32_16x16x32_bf16(a0, xf, (f32x4)0.f, 0, 0, 0);
            yacc[ctl][1] = __builtin_amdgcn_mfma_f32_16x16x32_bf16(a1, xf, (f32x4)0.f, 0, 0, 0);
        }
    }
    __syncthreads();
    #pragma unroll
    for (int ctl = 0; ctl < 4; ++ctl) {
        int c = wv * 64 + ctl * 16 + l15;
        #pragma unroll
        for (int mt = 0; mt < 2; ++mt)
            #pragma unroll
            for (int r = 0; r < 4; ++r) {
                int m = mt * 16 + quad * 4 + r;
                ys[m * YS + c] = (__bf16)yacc[ctl][mt][r];
            }
    }
    __syncthreads();

    const int o0 = wv * 64;
    f32x4 acc[4][2];
    #pragma unroll
    for (int ot = 0; ot < 4; ++ot)
        #pragma unroll
        for (int mt = 0; mt < 2; ++mt) acc[ot][mt] = (f32x4)0.f;
    #pragma unroll 2
    for (int kk = 0; kk < 8; ++kk) {
        const int k = kk * 32 + quad * 8;
        bf16x8 bfr[2];
        #pragma unroll
        for (int mt = 0; mt < 2; ++mt)
            bfr[mt] = *(const bf16x8*)&ys[(mt * 16 + l15) * YS + k];
        #pragma unroll
        for (int ot = 0; ot < 4; ++ot) {
            bf16x8 af = *(const bf16x8*)&Wb[(size_t)(o0 + ot * 16 + l15) * C + k];
            #pragma unroll
            for (int mt = 0; mt < 2; ++mt)
                acc[ot][mt] = __builtin_amdgcn_mfma_f32_16x16x32_bf16(af, bfr[mt], acc[ot][mt], 0, 0, 0);
        }
    }
    float* outb = out + (size_t)b * (C * N);
    #pragma unroll
    for (int ot = 0; ot < 4; ++ot)
        #pragma unroll
        for (int mt = 0; mt < 2; ++mt) {
            const int m = mt * 16 + l15;
            if (m < N) {
                #pragma unroll
                for (int r = 0; r < 4; ++r) {
                    const int o = o0 + ot * 16 + quad * 4 + r;
                    float v = acc[ot][mt][r] + biasS[o] * adjS[m] + xb[o * N + m];
                    outb[o * N + m] = v > 0.f ? v : 0.f;
                }
            }
        }
}

extern "C" void kernel_launch(void* const* d_in, const int* in_sizes, int n_in,
                              void* d_out, int out_size, void* d_ws, size_t ws_size,
                              hipStream_t stream) {
    (void)in_sizes; (void)n_in; (void)out_size;
    const float* x    = (const float*)d_in[0];   // [4096, 256, 25]
    const float* adj  = (const float*)d_in[1];   // [25, 25]
    const float* W    = (const float*)d_in[2];   // [256, 256]
    const float* bias = (const float*)d_in[3];   // [256]
    float* out = (float*)d_out;

    unsigned char* ws = (unsigned char*)d_ws;
    __bf16* Wb   = (__bf16*)ws;                       // 131072 B
    float*  adjS = (float*)(ws + 131072);             // 128 B
    __bf16* y    = (__bf16*)(ws + 132 * 1024);        // 4096*32*256*2 = 64 MiB
    const size_t need = 132 * 1024 + (size_t)BATCH * YB * sizeof(__bf16);

    if (ws_size >= need) {
        prep_kernel<<<(C * C) / 256, 256, 0, stream>>>(W, adj, Wb, adjS);
        agg_kernel<<<BATCH, 256, 0, stream>>>(x, adj, y);
        gemm_kernel<<<BATCH, 256, 0, stream>>>(x, bias, adjS, Wb, y, out);
    } else {
        prep_kernel<<<(C * C) / 256, 256, 0, stream>>>(W, adj, Wb, adjS);
        gcn_fused_kernel<<<BATCH, 256, 0, stream>>>(x, adj, bias, Wb, out);
    }
}